// Round 3
// baseline (129.802 us; speedup 1.0000x reference)
//
#include <hip/hip_runtime.h>
#include <hip/hip_bf16.h>

#define B_ 8
#define T_ 4096
#define D_ 128
#define H_ 64
#define SBLK 64
#define NT (T_ / SBLK)

typedef short bf16x8 __attribute__((ext_vector_type(8)));
typedef float f32x4 __attribute__((ext_vector_type(4)));
typedef float f32x16 __attribute__((ext_vector_type(16)));

__device__ __forceinline__ unsigned short f2bf(float f) {
  unsigned int u = __float_as_uint(f);
  u += 0x7fffu + ((u >> 16) & 1u);   // RNE
  return (unsigned short)(u >> 16);
}

__device__ __forceinline__ void async_copy16(const void* g, void* l) {
  __builtin_amdgcn_global_load_lds((const __attribute__((address_space(1))) void*)g,
                                   (__attribute__((address_space(3))) void*)l, 16, 0, 0);
}

// ---- workspace layout (bytes) ----
#define OFF_XP  0u
#define SZ_XP   ((unsigned)(B_*(T_+2)*D_*2))      // padded bf16 X, zero rows at batch edges
#define OFF_XT  (OFF_XP + SZ_XP)
#define SZ_XT   ((unsigned)(B_*D_*T_*2))          // V^T bf16 [B][128][T]
#define OFF_F   (OFF_XT + SZ_XT)
#define SZ_F    ((unsigned)(B_*T_*H_*2))
#define OFF_G   (OFF_F + SZ_F)
#define OFF_WFT (OFF_G + SZ_F)
#define SZ_WFT  ((unsigned)(H_*D_*2))
#define OFF_WGT (OFF_WFT + SZ_WFT)

// ---------------- kernel 1: cast X -> Xp (padded bf16) and transpose -> XT ----------------
__global__ __launch_bounds__(256) void prep_x(const float* __restrict__ X,
                                              unsigned short* __restrict__ Xp,
                                              unsigned short* __restrict__ XT) {
  __shared__ unsigned short tile[64][129];   // +1 pad: conflict-free column reads
  const int b = blockIdx.x;
  const int t0 = blockIdx.y * 64;
  const int tid = threadIdx.x;
#pragma unroll
  for (int c = 0; c < 8; ++c) {
    int i4 = tid + c * 256;               // 0..2047 float4 chunks of the 64x128 tile
    int row = i4 >> 5, col4 = i4 & 31;
    float4 v = ((const float4*)X)[(size_t)(b * T_ + t0 + row) * 32 + col4];
    ushort4 h;
    h.x = f2bf(v.x); h.y = f2bf(v.y); h.z = f2bf(v.z); h.w = f2bf(v.w);
    ((ushort4*)Xp)[(size_t)(b * (T_ + 2) + 1 + t0 + row) * 32 + col4] = h;
    tile[row][col4 * 4 + 0] = h.x;
    tile[row][col4 * 4 + 1] = h.y;
    tile[row][col4 * 4 + 2] = h.z;
    tile[row][col4 * 4 + 3] = h.w;
  }
  if (blockIdx.y == 0 && tid < 32) {       // zero pad rows (conv boundary)
    ushort4 z = {0, 0, 0, 0};
    ((ushort4*)Xp)[(size_t)(b * (T_ + 2) + 0) * 32 + tid] = z;
    ((ushort4*)Xp)[(size_t)(b * (T_ + 2) + T_ + 1) * 32 + tid] = z;
  }
  __syncthreads();
#pragma unroll
  for (int c = 0; c < 8; ++c) {
    int o4 = tid + c * 256;               // 0..2047 ushort4 chunks of XT tile
    int d = o4 >> 4, t4 = o4 & 15;
    ushort4 h;
    h.x = tile[t4 * 4 + 0][d];
    h.y = tile[t4 * 4 + 1][d];
    h.z = tile[t4 * 4 + 2][d];
    h.w = tile[t4 * 4 + 3][d];
    ((ushort4*)XT)[(size_t)(b * 128 + d) * (T_ / 4) + (t0 >> 2) + t4] = h;
  }
}

// ---------------- kernel 2: weights -> transposed bf16 (Wf pre-scaled by log2e/8) ----------------
__global__ __launch_bounds__(256) void prep_w(const float* __restrict__ Wf,
                                              const float* __restrict__ Wg,
                                              unsigned short* __restrict__ WfT,
                                              unsigned short* __restrict__ WgT) {
  const float SC = 0.18033688011112042f;  // (1/sqrt(64)) * log2(e)
  int idx = blockIdx.x * 256 + threadIdx.x;    // 0..32767
  if (idx < H_ * D_) {
    int h = idx >> 7, d = idx & 127;
    WfT[idx] = f2bf(Wf[d * H_ + h] * SC);
  } else {
    int j = idx - H_ * D_;                     // 0..24575
    int tap = j >> 13, r = j & 8191;
    int h = r >> 7, d = r & 127;
    WgT[j] = f2bf(Wg[tap * (D_ * H_) + d * H_ + h]);
  }
}

// ---------------- kernel 3: F = Xp[t+1]*Wf (pre-scaled), G = sum_taps Xp[t+s]*Wg[s] ----------------
// 32 rows/block, 1024 blocks -> 4 waves/CU for latency hiding.
__global__ __launch_bounds__(64) void fg_kernel(const unsigned short* __restrict__ Xp,
                                                const unsigned short* __restrict__ WfT,
                                                const unsigned short* __restrict__ WgT,
                                                unsigned short* __restrict__ F,
                                                unsigned short* __restrict__ G) {
  const int lane = threadIdx.x;
  const int rowbase = blockIdx.x * 32;         // global (b,t) row
  const int b = rowbase >> 12, t0 = rowbase & (T_ - 1);
  const int l15 = lane & 15, lhi = lane >> 4;
  const f32x4 fz = {0.f, 0.f, 0.f, 0.f};
  f32x4 accF[2][4], accG[2][4];
#pragma unroll
  for (int mt = 0; mt < 2; ++mt)
#pragma unroll
    for (int nt = 0; nt < 4; ++nt) { accF[mt][nt] = fz; accG[mt][nt] = fz; }

#pragma unroll
  for (int kk = 0; kk < 4; ++kk) {
    const int k0 = kk * 32 + lhi * 8;
    bf16x8 a[3][2];
#pragma unroll
    for (int sh = 0; sh < 3; ++sh)
#pragma unroll
      for (int mt = 0; mt < 2; ++mt) {
        int r = b * (T_ + 2) + t0 + sh + mt * 16 + l15;
        a[sh][mt] = *(const bf16x8*)&Xp[(size_t)r * 128 + k0];
      }
#pragma unroll
    for (int nt = 0; nt < 4; ++nt) {
      int h = nt * 16 + l15;
      bf16x8 wf  = *(const bf16x8*)&WfT[h * 128 + k0];
      bf16x8 wg0 = *(const bf16x8*)&WgT[(0 * 64 + h) * 128 + k0];
      bf16x8 wg1 = *(const bf16x8*)&WgT[(1 * 64 + h) * 128 + k0];
      bf16x8 wg2 = *(const bf16x8*)&WgT[(2 * 64 + h) * 128 + k0];
#pragma unroll
      for (int mt = 0; mt < 2; ++mt) {
        accF[mt][nt] = __builtin_amdgcn_mfma_f32_16x16x32_bf16(a[1][mt], wf,  accF[mt][nt], 0, 0, 0);
        accG[mt][nt] = __builtin_amdgcn_mfma_f32_16x16x32_bf16(a[0][mt], wg0, accG[mt][nt], 0, 0, 0);
        accG[mt][nt] = __builtin_amdgcn_mfma_f32_16x16x32_bf16(a[1][mt], wg1, accG[mt][nt], 0, 0, 0);
        accG[mt][nt] = __builtin_amdgcn_mfma_f32_16x16x32_bf16(a[2][mt], wg2, accG[mt][nt], 0, 0, 0);
      }
    }
  }
#pragma unroll
  for (int mt = 0; mt < 2; ++mt)
#pragma unroll
    for (int nt = 0; nt < 4; ++nt)
#pragma unroll
      for (int r = 0; r < 4; ++r) {
        int t = t0 + mt * 16 + lhi * 4 + r;
        int h = nt * 16 + l15;
        size_t o = (size_t)(b * T_ + t) * 64 + h;
        F[o] = f2bf(accF[mt][nt][r]);
        G[o] = f2bf(accG[mt][nt][r]);
      }
}

// ---------------- kernel 4: flash attention, 32x32 MFMA, P fully in-register ----------------
// Swapped QK^T (S^T = K*Q^T): lane holds P-column fragment; redistribution to the PV
// A-fragment needs exchange only across lane+-32 -> one v_permlane32_swap_b32 per (ks,u)
// yields TWO target words (T12 pattern). No P LDS buffer at all.
__global__ __launch_bounds__(256) void attn_kernel(const unsigned short* __restrict__ F,
                                                   const unsigned short* __restrict__ G,
                                                   const unsigned short* __restrict__ XT,
                                                   float* __restrict__ out) {
  __shared__ unsigned short klds[2][64 * 64];    // 2 x 8KB,  [s][h] swizzled
  __shared__ unsigned short vlds[2][128 * 64];   // 2 x 16KB, [d][s] swizzled (V^T tile)
  const int b = blockIdx.x;
  const int q0 = blockIdx.y * 128;
  const int tid = threadIdx.x;
  const int wave = tid >> 6, lane = tid & 63;
  const int l31 = lane & 31, hi = lane >> 5;
  const int qw = q0 + wave * 32;
  const int E = (l31 & 7) << 4;                  // per-lane swizzle XOR constant

  // Q as 32x32x16 B-fragments: B[k][n=q]: lane n=l31, k = ks*16 + hi*8 + j
  bf16x8 qf[4];
#pragma unroll
  for (int ks = 0; ks < 4; ++ks)
    qf[ks] = *(const bf16x8*)&F[(size_t)(b * T_ + qw + l31) * 64 + ks * 16 + hi * 8];

  f32x16 o_acc[4];
  f32x16 sacc;
#pragma unroll
  for (int r = 0; r < 16; ++r) sacc[r] = 0.f;
#pragma unroll
  for (int nt = 0; nt < 4; ++nt)
#pragma unroll
    for (int r = 0; r < 16; ++r) o_acc[nt][r] = 0.f;
  bf16x8 ones;
#pragma unroll
  for (int j = 0; j < 8; ++j) ones[j] = (short)0x3F80;   // bf16 1.0

  const int lo3 = lane >> 3, lc = lane & 7;
  const int cp = lc ^ lo3;                       // pre-swizzled source chunk (row&7 == lo3)

  // stage one 64-s tile into buffer `buf` (K 8 x 1KB, V 16 x 1KB; 6 issues per wave)
  auto stage = [&](int buf, int s0n) {
#pragma unroll
    for (int i = 0; i < 2; ++i) {
      int kchunk = wave * 2 + i;                 // 0..7, rows s = kchunk*8 + lo3
      int s = kchunk * 8 + lo3;
      async_copy16(&G[(size_t)(b * T_ + s0n + s) * 64 + cp * 8],
                   (char*)&klds[buf][0] + kchunk * 1024);
    }
#pragma unroll
    for (int i = 0; i < 4; ++i) {
      int vchunk = wave * 4 + i;                 // 0..15, rows d = vchunk*8 + lo3
      int d = vchunk * 8 + lo3;
      async_copy16(&XT[(size_t)(b * 128 + d) * T_ + s0n + cp * 8],
                   (char*)&vlds[buf][0] + vchunk * 1024);
    }
  };

  stage(0, 0);
  __syncthreads();

  union PW { unsigned u[4]; bf16x8 v; };

  for (int t = 0; t < NT; ++t) {
    const int cur = t & 1;
    if (t + 1 < NT) stage(cur ^ 1, (t + 1) * SBLK);   // overlap next-tile DMA with compute

    char* kbase = (char*)klds[cur];
    char* vbase = (char*)vlds[cur];

    // S^T = K*Q^T, two 32-s tiles. A[m=s][k]: row = st*32+l31, k = ks*16+hi*8+j.
    f32x16 S0, S1;
#pragma unroll
    for (int r = 0; r < 16; ++r) { S0[r] = 0.f; S1[r] = 0.f; }
#pragma unroll
    for (int ks = 0; ks < 4; ++ks) {
      bf16x8 k0 = *(const bf16x8*)(kbase + ((0 * 32 + l31) * 128 + ((ks * 32 + hi * 16) ^ E)));
      bf16x8 k1 = *(const bf16x8*)(kbase + ((1 * 32 + l31) * 128 + ((ks * 32 + hi * 16) ^ E)));
      S0 = __builtin_amdgcn_mfma_f32_32x32x16_bf16(k0, qf[ks], S0, 0, 0, 0);
      S1 = __builtin_amdgcn_mfma_f32_32x32x16_bf16(k1, qf[ks], S1, 0, 0, 0);
    }

    // P = exp2(S^T) -> bf16 words -> permlane32_swap -> PV A-fragments (in-register).
    // Lane (l31,hi) reg r holds s_local = (r&3) + 8*(r>>2) + 4*hi, q = l31.
    // Word w[g][u] = pack(p[4g+2u], p[4g+2u+1]) covers s-pair (8g+4hi+2u, +1).
    // Target paw[ksl][v] = w[2ksl+hi][v&1] taken from half hi_src = v>>1.
    bf16x8 pa[4];
#pragma unroll
    for (int st = 0; st < 2; ++st) {
      const f32x16& S = st ? S1 : S0;
      float p[16];
#pragma unroll
      for (int r = 0; r < 16; ++r) p[r] = __builtin_amdgcn_exp2f(S[r]);
      unsigned w[4][2];
#pragma unroll
      for (int g = 0; g < 4; ++g)
#pragma unroll
        for (int u = 0; u < 2; ++u) {
          union { __hip_bfloat162 h2; unsigned uu; } cv;
          cv.h2 = __float22bfloat162_rn(make_float2(p[4 * g + 2 * u], p[4 * g + 2 * u + 1]));
          w[g][u] = cv.uu;
        }
#pragma unroll
      for (int ksl = 0; ksl < 2; ++ksl) {
        PW pw;
#pragma unroll
        for (int u = 0; u < 2; ++u) {
          unsigned A = w[2 * ksl][u], Bv = w[2 * ksl + 1][u];
          asm("v_permlane32_swap_b32 %0, %1" : "+v"(A), "+v"(Bv));
          pw.u[u] = A;          // s-pair (ksl*16 + hi*8 + 2u, +1)
          pw.u[2 + u] = Bv;     // s-pair (ksl*16 + hi*8 + 4 + 2u, +1)
        }
        pa[st * 2 + ksl] = pw.v;
      }
    }

    // row-sums via ones-fragment MFMA (accumulates l across all tiles)
#pragma unroll
    for (int ks = 0; ks < 4; ++ks)
      sacc = __builtin_amdgcn_mfma_f32_32x32x16_bf16(pa[ks], ones, sacc, 0, 0, 0);

    // O += P * V : B[n=d][k=s]: row = nt*32+l31, k-bytes = ks*32 + hi*16
#pragma unroll
    for (int nt = 0; nt < 4; ++nt) {
#pragma unroll
      for (int ks = 0; ks < 4; ++ks) {
        bf16x8 vf = *(const bf16x8*)(vbase + ((nt * 32 + l31) * 128 + ((ks * 32 + hi * 16) ^ E)));
        o_acc[nt] = __builtin_amdgcn_mfma_f32_32x32x16_bf16(pa[ks], vf, o_acc[nt], 0, 0, 0);
      }
    }
    __syncthreads();   // all waves done reading buf[cur]; stage of buf[cur^1] drained
  }

  // epilogue: out = O / l  (fp32). Row q = (r&3) + 8*(r>>2) + 4*hi, col d = nt*32 + l31.
#pragma unroll
  for (int r = 0; r < 16; ++r) {
    float inv = 1.0f / sacc[r];
    int trow = qw + (r & 3) + 8 * (r >> 2) + 4 * hi;
#pragma unroll
    for (int nt = 0; nt < 4; ++nt)
      out[(size_t)(b * T_ + trow) * 128 + nt * 32 + l31] = o_acc[nt][r] * inv;
  }
}

extern "C" void kernel_launch(void* const* d_in, const int* in_sizes, int n_in,
                              void* d_out, int out_size, void* d_ws, size_t ws_size,
                              hipStream_t stream) {
  (void)in_sizes; (void)n_in; (void)out_size; (void)ws_size;
  const float* X  = (const float*)d_in[0];
  const float* Wf = (const float*)d_in[1];
  const float* Wg = (const float*)d_in[2];
  float* out = (float*)d_out;
  char* ws = (char*)d_ws;
  unsigned short* Xp  = (unsigned short*)(ws + OFF_XP);
  unsigned short* XT  = (unsigned short*)(ws + OFF_XT);
  unsigned short* Fb  = (unsigned short*)(ws + OFF_F);
  unsigned short* Gb  = (unsigned short*)(ws + OFF_G);
  unsigned short* WfT = (unsigned short*)(ws + OFF_WFT);
  unsigned short* WgT = (unsigned short*)(ws + OFF_WGT);

  prep_x<<<dim3(B_, T_ / 64), 256, 0, stream>>>(X, Xp, XT);
  prep_w<<<(H_ * D_ * 4) / 256, 256, 0, stream>>>(Wf, Wg, WfT, WgT);
  fg_kernel<<<(B_ * T_) / 32, 64, 0, stream>>>(Xp, WfT, WgT, Fb, Gb);
  attn_kernel<<<dim3(B_, T_ / 128), 256, 0, stream>>>(Fb, Gb, XT, out);
}

// Round 4
// 100.912 us; speedup vs baseline: 1.2863x; 1.2863x over previous
//
#include <hip/hip_runtime.h>
#include <hip/hip_bf16.h>

#define B_ 8
#define T_ 4096
#define D_ 128
#define H_ 64
#define SBLK 64
#define NT (T_ / SBLK)
#define NT2 (NT / 2)          // tiles per s-split

typedef short bf16x8 __attribute__((ext_vector_type(8)));
typedef float f32x4 __attribute__((ext_vector_type(4)));
typedef float f32x16 __attribute__((ext_vector_type(16)));

__device__ __forceinline__ unsigned short f2bf(float f) {
  unsigned int u = __float_as_uint(f);
  u += 0x7fffu + ((u >> 16) & 1u);   // RNE
  return (unsigned short)(u >> 16);
}

__device__ __forceinline__ void async_copy16(const void* g, void* l) {
  __builtin_amdgcn_global_load_lds((const __attribute__((address_space(1))) void*)g,
                                   (__attribute__((address_space(3))) void*)l, 16, 0, 0);
}

// ---- workspace layout (bytes) ----
#define OFF_XP  0u
#define SZ_XP   ((unsigned)(B_*(T_+2)*D_*2))      // padded bf16 X; DEAD after fg -> reused as PO0
#define OFF_XT  (OFF_XP + SZ_XP)
#define SZ_XT   ((unsigned)(B_*D_*T_*2))          // V^T bf16 [B][128][T]
#define OFF_F   (OFF_XT + SZ_XT)
#define SZ_F    ((unsigned)(B_*T_*H_*2))
#define OFF_G   (OFF_F + SZ_F)
#define OFF_WFT (OFF_G + SZ_F)
#define SZ_WFT  ((unsigned)(H_*D_*2))
#define OFF_WGT (OFF_WFT + SZ_WFT)
#define SZ_WGT  ((unsigned)(3*H_*D_*2))
#define OFF_PO1 (OFF_WGT + SZ_WGT)                // split-0 O-partial, q in [2048,4096)
#define SZ_PO1  ((unsigned)(B_*2048*D_*4))
#define OFF_PL  (OFF_PO1 + SZ_PO1)               // l-partials [2][B][T] fp32

// bank-slot swizzle: distinct slots for row-pairs differing by 1..8 or 16 (all HW
// b128 lane-grouping hypotheses). Read-side value is a per-lane constant.
#define SLOT(r) (((((r) & 3) << 1) ^ (((r) >> 2) & 1) ^ (((((r) >> 3) ^ ((r) >> 4)) & 1) << 2)))

// ---------------- kernel 1: cast X -> Xp (padded bf16) and transpose -> XT ----------------
__global__ __launch_bounds__(256) void prep_x(const float* __restrict__ X,
                                              unsigned short* __restrict__ Xp,
                                              unsigned short* __restrict__ XT) {
  __shared__ unsigned short tile[64][129];   // +1 pad: conflict-free column reads
  const int b = blockIdx.x;
  const int t0 = blockIdx.y * 64;
  const int tid = threadIdx.x;
#pragma unroll
  for (int c = 0; c < 8; ++c) {
    int i4 = tid + c * 256;               // 0..2047 float4 chunks of the 64x128 tile
    int row = i4 >> 5, col4 = i4 & 31;
    float4 v = ((const float4*)X)[(size_t)(b * T_ + t0 + row) * 32 + col4];
    ushort4 h;
    h.x = f2bf(v.x); h.y = f2bf(v.y); h.z = f2bf(v.z); h.w = f2bf(v.w);
    ((ushort4*)Xp)[(size_t)(b * (T_ + 2) + 1 + t0 + row) * 32 + col4] = h;
    tile[row][col4 * 4 + 0] = h.x;
    tile[row][col4 * 4 + 1] = h.y;
    tile[row][col4 * 4 + 2] = h.z;
    tile[row][col4 * 4 + 3] = h.w;
  }
  if (blockIdx.y == 0 && tid < 32) {       // zero pad rows (conv boundary)
    ushort4 z = {0, 0, 0, 0};
    ((ushort4*)Xp)[(size_t)(b * (T_ + 2) + 0) * 32 + tid] = z;
    ((ushort4*)Xp)[(size_t)(b * (T_ + 2) + T_ + 1) * 32 + tid] = z;
  }
  __syncthreads();
#pragma unroll
  for (int c = 0; c < 8; ++c) {
    int o4 = tid + c * 256;               // 0..2047 ushort4 chunks of XT tile
    int d = o4 >> 4, t4 = o4 & 15;
    ushort4 h;
    h.x = tile[t4 * 4 + 0][d];
    h.y = tile[t4 * 4 + 1][d];
    h.z = tile[t4 * 4 + 2][d];
    h.w = tile[t4 * 4 + 3][d];
    ((ushort4*)XT)[(size_t)(b * 128 + d) * (T_ / 4) + (t0 >> 2) + t4] = h;
  }
}

// ---------------- kernel 2: weights -> transposed bf16 (Wf pre-scaled by log2e/8) ----------------
__global__ __launch_bounds__(256) void prep_w(const float* __restrict__ Wf,
                                              const float* __restrict__ Wg,
                                              unsigned short* __restrict__ WfT,
                                              unsigned short* __restrict__ WgT) {
  const float SC = 0.18033688011112042f;  // (1/sqrt(64)) * log2(e)
  int idx = blockIdx.x * 256 + threadIdx.x;    // 0..32767
  if (idx < H_ * D_) {
    int h = idx >> 7, d = idx & 127;
    WfT[idx] = f2bf(Wf[d * H_ + h] * SC);
  } else {
    int j = idx - H_ * D_;                     // 0..24575
    int tap = j >> 13, r = j & 8191;
    int h = r >> 7, d = r & 127;
    WgT[j] = f2bf(Wg[tap * (D_ * H_) + d * H_ + h]);
  }
}

// ---------------- kernel 3: F = Xp[t+1]*Wf (pre-scaled), G = sum_taps Xp[t+s]*Wg[s] ----------------
__global__ __launch_bounds__(64) void fg_kernel(const unsigned short* __restrict__ Xp,
                                                const unsigned short* __restrict__ WfT,
                                                const unsigned short* __restrict__ WgT,
                                                unsigned short* __restrict__ F,
                                                unsigned short* __restrict__ G) {
  const int lane = threadIdx.x;
  const int rowbase = blockIdx.x * 32;         // global (b,t) row
  const int b = rowbase >> 12, t0 = rowbase & (T_ - 1);
  const int l15 = lane & 15, lhi = lane >> 4;
  const f32x4 fz = {0.f, 0.f, 0.f, 0.f};
  f32x4 accF[2][4], accG[2][4];
#pragma unroll
  for (int mt = 0; mt < 2; ++mt)
#pragma unroll
    for (int nt = 0; nt < 4; ++nt) { accF[mt][nt] = fz; accG[mt][nt] = fz; }

#pragma unroll
  for (int kk = 0; kk < 4; ++kk) {
    const int k0 = kk * 32 + lhi * 8;
    bf16x8 a[3][2];
#pragma unroll
    for (int sh = 0; sh < 3; ++sh)
#pragma unroll
      for (int mt = 0; mt < 2; ++mt) {
        int r = b * (T_ + 2) + t0 + sh + mt * 16 + l15;
        a[sh][mt] = *(const bf16x8*)&Xp[(size_t)r * 128 + k0];
      }
#pragma unroll
    for (int nt = 0; nt < 4; ++nt) {
      int h = nt * 16 + l15;
      bf16x8 wf  = *(const bf16x8*)&WfT[h * 128 + k0];
      bf16x8 wg0 = *(const bf16x8*)&WgT[(0 * 64 + h) * 128 + k0];
      bf16x8 wg1 = *(const bf16x8*)&WgT[(1 * 64 + h) * 128 + k0];
      bf16x8 wg2 = *(const bf16x8*)&WgT[(2 * 64 + h) * 128 + k0];
#pragma unroll
      for (int mt = 0; mt < 2; ++mt) {
        accF[mt][nt] = __builtin_amdgcn_mfma_f32_16x16x32_bf16(a[1][mt], wf,  accF[mt][nt], 0, 0, 0);
        accG[mt][nt] = __builtin_amdgcn_mfma_f32_16x16x32_bf16(a[0][mt], wg0, accG[mt][nt], 0, 0, 0);
        accG[mt][nt] = __builtin_amdgcn_mfma_f32_16x16x32_bf16(a[1][mt], wg1, accG[mt][nt], 0, 0, 0);
        accG[mt][nt] = __builtin_amdgcn_mfma_f32_16x16x32_bf16(a[2][mt], wg2, accG[mt][nt], 0, 0, 0);
      }
    }
  }
#pragma unroll
  for (int mt = 0; mt < 2; ++mt)
#pragma unroll
    for (int nt = 0; nt < 4; ++nt)
#pragma unroll
      for (int r = 0; r < 4; ++r) {
        int t = t0 + mt * 16 + lhi * 4 + r;
        int h = nt * 16 + l15;
        size_t o = (size_t)(b * T_ + t) * 64 + h;
        F[o] = f2bf(accF[mt][nt][r]);
        G[o] = f2bf(accG[mt][nt][r]);
      }
}

// ---------------- kernel 4: flash attention, 32x32 MFMA, in-register P, s-split x2 ----------------
// Fixed-max softmax (P = exp2(S)) makes s-split partials ADDITIVE: split z accumulates
// O,l over its half of the key range; merge kernel computes (O0+O1)/(l0+l1).
__global__ __launch_bounds__(256) void attn_kernel(const unsigned short* __restrict__ F,
                                                   const unsigned short* __restrict__ G,
                                                   const unsigned short* __restrict__ XT,
                                                   float* __restrict__ out,
                                                   float* __restrict__ PO0,
                                                   float* __restrict__ PO1,
                                                   float* __restrict__ PL) {
  __shared__ unsigned short klds[2][64 * 64];    // 2 x 8KB,  [s][h] slot-swizzled
  __shared__ unsigned short vlds[2][128 * 64];   // 2 x 16KB, [d][s] slot-swizzled (V^T tile)
  const int b = blockIdx.x;
  const int q0 = blockIdx.y * 128;
  const int z = blockIdx.z;                      // s-split index
  const int tid = threadIdx.x;
  const int wave = tid >> 6, lane = tid & 63;
  const int l31 = lane & 31, hi = lane >> 5;
  const int qw = q0 + wave * 32;
  const int E = SLOT(l31) << 4;                  // per-lane read-swizzle constant

  // Q as 32x32x16 B-fragments: B[k][n=q]: lane n=l31, k = ks*16 + hi*8 + j
  bf16x8 qf[4];
#pragma unroll
  for (int ks = 0; ks < 4; ++ks)
    qf[ks] = *(const bf16x8*)&F[(size_t)(b * T_ + qw + l31) * 64 + ks * 16 + hi * 8];

  f32x16 o_acc[4];
  f32x16 sacc;
#pragma unroll
  for (int r = 0; r < 16; ++r) sacc[r] = 0.f;
#pragma unroll
  for (int nt = 0; nt < 4; ++nt)
#pragma unroll
    for (int r = 0; r < 16; ++r) o_acc[nt][r] = 0.f;
  bf16x8 ones;
#pragma unroll
  for (int j = 0; j < 8; ++j) ones[j] = (short)0x3F80;   // bf16 1.0

  const int lo3 = lane >> 3, lc = lane & 7;

  // stage one 64-s tile (K 8 x 1KB, V 16 x 1KB; 6 issues per wave). LDS dest is linear
  // (gload_lds rule); source chunk pre-swizzled to match SLOT read layout.
  auto stage = [&](int buf, int s0n) {
#pragma unroll
    for (int i = 0; i < 2; ++i) {
      int kchunk = wave * 2 + i;                 // rows s = kchunk*8 + lo3
      int s = kchunk * 8 + lo3;
      int cp = lc ^ ((lo3 & 3) << 1) ^ ((lo3 >> 2) & 1) ^ (((kchunk ^ (kchunk >> 1)) & 1) << 2);
      async_copy16(&G[(size_t)(b * T_ + s0n + s) * 64 + cp * 8],
                   (char*)&klds[buf][0] + kchunk * 1024);
    }
#pragma unroll
    for (int i = 0; i < 4; ++i) {
      int vchunk = wave * 4 + i;                 // rows d = vchunk*8 + lo3
      int d = vchunk * 8 + lo3;
      int cp = lc ^ ((lo3 & 3) << 1) ^ ((lo3 >> 2) & 1) ^ (((vchunk ^ (vchunk >> 1)) & 1) << 2);
      async_copy16(&XT[(size_t)(b * 128 + d) * T_ + s0n + cp * 8],
                   (char*)&vlds[buf][0] + vchunk * 1024);
    }
  };

  stage(0, z * NT2 * SBLK);
  __syncthreads();

  union PW { unsigned u[4]; bf16x8 v; };

  for (int tt = 0; tt < NT2; ++tt) {
    const int cur = tt & 1;
    if (tt + 1 < NT2) stage(cur ^ 1, (z * NT2 + tt + 1) * SBLK);
    __builtin_amdgcn_s_setprio(1);

    char* kbase = (char*)klds[cur];
    char* vbase = (char*)vlds[cur];

    // S^T = K*Q^T, two 32-s tiles. A[m=s][k]: row = st*32+l31, k-bytes = ks*32+hi*16.
    f32x16 S0, S1;
#pragma unroll
    for (int r = 0; r < 16; ++r) { S0[r] = 0.f; S1[r] = 0.f; }
#pragma unroll
    for (int ks = 0; ks < 4; ++ks) {
      bf16x8 k0 = *(const bf16x8*)(kbase + ((0 * 32 + l31) * 128 + ((ks * 32 + hi * 16) ^ E)));
      bf16x8 k1 = *(const bf16x8*)(kbase + ((1 * 32 + l31) * 128 + ((ks * 32 + hi * 16) ^ E)));
      S0 = __builtin_amdgcn_mfma_f32_32x32x16_bf16(k0, qf[ks], S0, 0, 0, 0);
      S1 = __builtin_amdgcn_mfma_f32_32x32x16_bf16(k1, qf[ks], S1, 0, 0, 0);
    }

    // P = exp2(S^T) -> bf16 words -> permlane32_swap -> PV A-fragments (in-register, T12).
    bf16x8 pa[4];
#pragma unroll
    for (int st = 0; st < 2; ++st) {
      const f32x16& S = st ? S1 : S0;
      float p[16];
#pragma unroll
      for (int r = 0; r < 16; ++r) p[r] = __builtin_amdgcn_exp2f(S[r]);
      unsigned w[4][2];
#pragma unroll
      for (int g = 0; g < 4; ++g)
#pragma unroll
        for (int u = 0; u < 2; ++u) {
          union { __hip_bfloat162 h2; unsigned uu; } cv;
          cv.h2 = __float22bfloat162_rn(make_float2(p[4 * g + 2 * u], p[4 * g + 2 * u + 1]));
          w[g][u] = cv.uu;
        }
#pragma unroll
      for (int ksl = 0; ksl < 2; ++ksl) {
        PW pw;
#pragma unroll
        for (int u = 0; u < 2; ++u) {
          unsigned A = w[2 * ksl][u], Bv = w[2 * ksl + 1][u];
          asm("v_permlane32_swap_b32 %0, %1" : "+v"(A), "+v"(Bv));
          pw.u[u] = A;
          pw.u[2 + u] = Bv;
        }
        pa[st * 2 + ksl] = pw.v;
      }
    }

    // row-sums via ones-fragment MFMA
#pragma unroll
    for (int ks = 0; ks < 4; ++ks)
      sacc = __builtin_amdgcn_mfma_f32_32x32x16_bf16(pa[ks], ones, sacc, 0, 0, 0);

    // O += P * V : B[n=d][k=s]: row = nt*32+l31
#pragma unroll
    for (int nt = 0; nt < 4; ++nt) {
#pragma unroll
      for (int ks = 0; ks < 4; ++ks) {
        bf16x8 vf = *(const bf16x8*)(vbase + ((nt * 32 + l31) * 128 + ((ks * 32 + hi * 16) ^ E)));
        o_acc[nt] = __builtin_amdgcn_mfma_f32_32x32x16_bf16(pa[ks], vf, o_acc[nt], 0, 0, 0);
      }
    }
    __builtin_amdgcn_s_setprio(0);
    __syncthreads();
  }

  // epilogue: write RAW partials (merge kernel divides).
  // Row q = (r&3) + 8*(r>>2) + 4*hi, col d = nt*32 + l31.
  if (z == 1) {
#pragma unroll
    for (int r = 0; r < 16; ++r) {
      int trow = qw + (r & 3) + 8 * (r >> 2) + 4 * hi;
#pragma unroll
      for (int nt = 0; nt < 4; ++nt)
        out[(size_t)(b * T_ + trow) * 128 + nt * 32 + l31] = o_acc[nt][r];
    }
  } else {
    float* po = (q0 < 2048) ? PO0 : PO1;
#pragma unroll
    for (int r = 0; r < 16; ++r) {
      int trow = qw + (r & 3) + 8 * (r >> 2) + 4 * hi;
#pragma unroll
      for (int nt = 0; nt < 4; ++nt)
        po[(size_t)(b * 2048 + (trow & 2047)) * 128 + nt * 32 + l31] = o_acc[nt][r];
    }
  }
  if (l31 == 0) {
#pragma unroll
    for (int r = 0; r < 16; ++r) {
      int trow = qw + (r & 3) + 8 * (r >> 2) + 4 * hi;
      PL[z * (B_ * T_) + b * T_ + trow] = sacc[r];
    }
  }
}

// ---------------- kernel 5: out = (out + PO) / (l0 + l1) ----------------
__global__ __launch_bounds__(256) void merge_kernel(const float* __restrict__ PO0,
                                                    const float* __restrict__ PO1,
                                                    const float* __restrict__ PL,
                                                    float* __restrict__ out) {
  int idx = blockIdx.x * 256 + threadIdx.x;      // float4 index, 0..B*T*D/4-1
  int row = idx >> 5;                            // b*T + t
  int b = row >> 12, t = row & (T_ - 1);
  const float4* po = (t < 2048) ? (const float4*)PO0 : (const float4*)PO1;
  float4 o = ((const float4*)out)[idx];
  float4 p = po[(size_t)(b * 2048 + (t & 2047)) * 32 + (idx & 31)];
  float inv = 1.0f / (PL[row] + PL[B_ * T_ + row]);
  float4 r;
  r.x = (o.x + p.x) * inv;
  r.y = (o.y + p.y) * inv;
  r.z = (o.z + p.z) * inv;
  r.w = (o.w + p.w) * inv;
  ((float4*)out)[idx] = r;
}

extern "C" void kernel_launch(void* const* d_in, const int* in_sizes, int n_in,
                              void* d_out, int out_size, void* d_ws, size_t ws_size,
                              hipStream_t stream) {
  (void)in_sizes; (void)n_in; (void)out_size; (void)ws_size;
  const float* X  = (const float*)d_in[0];
  const float* Wf = (const float*)d_in[1];
  const float* Wg = (const float*)d_in[2];
  float* out = (float*)d_out;
  char* ws = (char*)d_ws;
  unsigned short* Xp  = (unsigned short*)(ws + OFF_XP);
  unsigned short* XT  = (unsigned short*)(ws + OFF_XT);
  unsigned short* Fb  = (unsigned short*)(ws + OFF_F);
  unsigned short* Gb  = (unsigned short*)(ws + OFF_G);
  unsigned short* WfT = (unsigned short*)(ws + OFF_WFT);
  unsigned short* WgT = (unsigned short*)(ws + OFF_WGT);
  float* PO0 = (float*)(ws + OFF_XP);            // overlays Xp (dead after fg_kernel)
  float* PO1 = (float*)(ws + OFF_PO1);
  float* PL  = (float*)(ws + OFF_PL);

  prep_x<<<dim3(B_, T_ / 64), 256, 0, stream>>>(X, Xp, XT);
  prep_w<<<(H_ * D_ * 4) / 256, 256, 0, stream>>>(Wf, Wg, WfT, WgT);
  fg_kernel<<<(B_ * T_) / 32, 64, 0, stream>>>(Xp, WfT, WgT, Fb, Gb);
  attn_kernel<<<dim3(B_, T_ / 128, 2), 256, 0, stream>>>(Fb, Gb, XT, out, PO0, PO1, PL);
  merge_kernel<<<(B_ * T_ * D_ / 4) / 256, 256, 0, stream>>>(PO0, PO1, PL, out);
}